// Round 4
// baseline (3956.181 us; speedup 1.0000x reference)
//
#include <hip/hip_runtime.h>
#include <math.h>

#define TB   720
#define NI   16
#define NH   128
#define NG   512   // 4*H
#define NB   256
#define PRED 96

__device__ __forceinline__ float sigf(float v) { return 1.0f / (1.0f + __expf(-v)); }

// ---------------- encoder ----------------
// grid 256 = (batch-pair) x (dir); block 1024.
// Thread task split so weight slice fits under the 128-VGPR allocator target
// (R2/R3: asking for 144+ regs made the compiler reload weights from L2 every
// step -> 30 TB/s L2-bound). t<512: row t over [x(16)|h(0:56)] (72 w + bias);
// t>=512: row t-512 over h(56:128) (72 w). Partials summed via LDS.
__global__ __launch_bounds__(1024, 4)
void enc_kernel(const float* __restrict__ x,
                const float* __restrict__ Wih_f, const float* __restrict__ Whh_f, const float* __restrict__ b_f,
                const float* __restrict__ Wih_b, const float* __restrict__ Whh_b, const float* __restrict__ b_b,
                float* __restrict__ st)   // st[b][dir][{h,c}][NH]
{
    __shared__ float xs0[TB * NI];
    __shared__ float xs1[TB * NI];
    __shared__ float hs0[NH], hs1[NH];
    __shared__ float ps0[1024], ps1[1024];

    const int wg  = blockIdx.x;
    const int dir = wg & 1;
    const int pb  = wg >> 1;
    const int b0  = 2 * pb, b1 = 2 * pb + 1;
    const int t   = threadIdx.x;
    const int half = t >> 9;       // 0: lower segment, 1: upper segment
    const int r    = t & 511;      // gate row

    const float* Wih = dir ? Wih_b : Wih_f;
    const float* Whh = dir ? Whh_b : Whh_f;
    const float* bv  = dir ? b_b   : b_f;

    // stage both batch elements' x (float4, coalesced)
    {
        const float4* xg0 = (const float4*)(x + (size_t)b0 * TB * NI);
        const float4* xg1 = (const float4*)(x + (size_t)b1 * TB * NI);
        float4* s0 = (float4*)xs0;
        float4* s1 = (float4*)xs1;
        for (int i = t; i < TB * NI / 4; i += 1024) { s0[i] = xg0[i]; s1[i] = xg1[i]; }
    }

    // weight segment -> registers (72 floats)
    float w[72];
    float bias = 0.0f;
    if (half == 0) {
#pragma unroll
        for (int k = 0; k < 4; ++k) {
            float4 v = ((const float4*)(Wih + r * NI))[k];
            w[4*k] = v.x; w[4*k+1] = v.y; w[4*k+2] = v.z; w[4*k+3] = v.w;
        }
#pragma unroll
        for (int k = 0; k < 14; ++k) {
            float4 v = ((const float4*)(Whh + r * NH))[k];
            w[16+4*k] = v.x; w[16+4*k+1] = v.y; w[16+4*k+2] = v.z; w[16+4*k+3] = v.w;
        }
        bias = bv[r];
    } else {
#pragma unroll
        for (int k = 0; k < 18; ++k) {
            float4 v = ((const float4*)(Whh + r * NH + 56))[k];
            w[4*k] = v.x; w[4*k+1] = v.y; w[4*k+2] = v.z; w[4*k+3] = v.w;
        }
    }

    if (t < NH) { hs0[t] = 0.0f; hs1[t] = 0.0f; }
    float cc = 0.0f;   // t<128: c of b0 dim t ; 512<=t<640: c of b1 dim t-512
    __syncthreads();

    for (int s = 0; s < TB; ++s) {
        const int tt = dir ? (TB - 1 - s) : s;
        float a0x = 0.f, a0y = 0.f, a0z = 0.f, a0w = 0.f;
        float a1x = 0.f, a1y = 0.f, a1z = 0.f, a1w = 0.f;
        if (half == 0) {
            const float4* xp0 = (const float4*)(xs0 + tt * NI);
            const float4* xp1 = (const float4*)(xs1 + tt * NI);
#pragma unroll
            for (int k = 0; k < 4; ++k) {
                float4 v0 = xp0[k], v1 = xp1[k];
                a0x += v0.x * w[4*k];   a0y += v0.y * w[4*k+1];
                a0z += v0.z * w[4*k+2]; a0w += v0.w * w[4*k+3];
                a1x += v1.x * w[4*k];   a1y += v1.y * w[4*k+1];
                a1z += v1.z * w[4*k+2]; a1w += v1.w * w[4*k+3];
            }
            const float4* h40 = (const float4*)hs0;
            const float4* h41 = (const float4*)hs1;
#pragma unroll
            for (int k = 0; k < 14; ++k) {
                float4 v0 = h40[k], v1 = h41[k];
                a0x += v0.x * w[16+4*k];   a0y += v0.y * w[16+4*k+1];
                a0z += v0.z * w[16+4*k+2]; a0w += v0.w * w[16+4*k+3];
                a1x += v1.x * w[16+4*k];   a1y += v1.y * w[16+4*k+1];
                a1z += v1.z * w[16+4*k+2]; a1w += v1.w * w[16+4*k+3];
            }
        } else {
            const float4* h40 = (const float4*)(hs0 + 56);
            const float4* h41 = (const float4*)(hs1 + 56);
#pragma unroll
            for (int k = 0; k < 18; ++k) {
                float4 v0 = h40[k], v1 = h41[k];
                a0x += v0.x * w[4*k];   a0y += v0.y * w[4*k+1];
                a0z += v0.z * w[4*k+2]; a0w += v0.w * w[4*k+3];
                a1x += v1.x * w[4*k];   a1y += v1.y * w[4*k+1];
                a1z += v1.z * w[4*k+2]; a1w += v1.w * w[4*k+3];
            }
        }
        ps0[t] = bias + (a0x + a0y) + (a0z + a0w);
        ps1[t] = bias + (a1x + a1y) + (a1z + a1w);
        __syncthreads();
        if (t < NH) {
            float gi = ps0[t]       + ps0[t + 512];
            float gf = ps0[t + 128] + ps0[t + 640];
            float gg = ps0[t + 256] + ps0[t + 768];
            float go = ps0[t + 384] + ps0[t + 896];
            cc = sigf(gf) * cc + sigf(gi) * tanhf(gg);
            hs0[t] = sigf(go) * tanhf(cc);
        } else if (t >= 512 && t < 512 + NH) {
            const int d = t - 512;
            float gi = ps1[d]       + ps1[d + 512];
            float gf = ps1[d + 128] + ps1[d + 640];
            float gg = ps1[d + 256] + ps1[d + 768];
            float go = ps1[d + 384] + ps1[d + 896];
            cc = sigf(gf) * cc + sigf(gi) * tanhf(gg);
            hs1[d] = sigf(go) * tanhf(cc);
        }
        __syncthreads();
    }

    if (t < NH) {
        st[((b0 * 2 + dir) * 2 + 0) * NH + t] = hs0[t];
        st[((b0 * 2 + dir) * 2 + 1) * NH + t] = cc;
    } else if (t >= 512 && t < 512 + NH) {
        const int d = t - 512;
        st[((b1 * 2 + dir) * 2 + 0) * NH + d] = hs1[d];
        st[((b1 * 2 + dir) * 2 + 1) * NH + d] = cc;
    }
}

// ---------------- decoder ----------------
// grid 256 (one WG per batch element); block 1024; t<512: f-cell row t,
// t>=512: b-cell row t-512. Full 144-weight row per thread (will clamp at
// ~128 VGPR and reload a little -- unavoidable: 147K weights / 1024 threads).
__global__ __launch_bounds__(1024, 4)
void dec_kernel(const float* __restrict__ x,
                const float* __restrict__ Wih_f, const float* __restrict__ Whh_f, const float* __restrict__ b_f,
                const float* __restrict__ Wih_b, const float* __restrict__ Whh_b, const float* __restrict__ b_b,
                const float* __restrict__ Wlin, const float* __restrict__ blin,
                const float* __restrict__ st, float* __restrict__ out)
{
    __shared__ float hF[NH], hB[NH];
    __shared__ float inp[NI];
    __shared__ float g[1024];    // f gates [0:512], b gates [512:1024]
    __shared__ float prt[NG];

    const int b    = blockIdx.x;
    const int t    = threadIdx.x;
    const int cell = t >> 9;     // 0 = f, 1 = b
    const int r    = t & 511;

    const float* Wih = cell ? Wih_b : Wih_f;
    const float* Whh = cell ? Whh_b : Whh_f;
    const float* bv  = cell ? b_b   : b_f;

    float u[NI];
#pragma unroll
    for (int k = 0; k < 4; ++k) {
        float4 v = ((const float4*)(Wih + r * NI))[k];
        u[4*k] = v.x; u[4*k+1] = v.y; u[4*k+2] = v.z; u[4*k+3] = v.w;
    }
    float w[NH];
#pragma unroll
    for (int k = 0; k < 32; ++k) {
        float4 v = ((const float4*)(Whh + r * NH))[k];
        w[4*k] = v.x; w[4*k+1] = v.y; w[4*k+2] = v.z; w[4*k+3] = v.w;
    }
    const float bias = bv[r];

    float cc = 0.0f;
    if (t < NH) {
        hF[t] = st[((b * 2 + 0) * 2 + 0) * NH + t];
        cc    = st[((b * 2 + 0) * 2 + 1) * NH + t];
    } else if (t >= 512 && t < 512 + NH) {
        const int d = t - 512;
        hB[d] = st[((b * 2 + 1) * 2 + 0) * NH + d];
        cc    = st[((b * 2 + 1) * 2 + 1) * NH + d];
    }
    if (t < NI) inp[t] = x[(size_t)b * TB * NI + (TB - 1) * NI + t];
    __syncthreads();

    for (int s = 0; s < PRED; ++s) {
        float ax = bias, ay = 0.f, az = 0.f, aw = 0.f;
        const float4* ip4 = (const float4*)inp;
#pragma unroll
        for (int k = 0; k < 4; ++k) {
            float4 v = ip4[k];
            ax += v.x * u[4*k];   ay += v.y * u[4*k+1];
            az += v.z * u[4*k+2]; aw += v.w * u[4*k+3];
        }
        const float4* h4 = cell ? (const float4*)hB : (const float4*)hF;
#pragma unroll
        for (int k = 0; k < 32; ++k) {
            float4 v = h4[k];
            ax += v.x * w[4*k];   ay += v.y * w[4*k+1];
            az += v.z * w[4*k+2]; aw += v.w * w[4*k+3];
        }
        g[t] = (ax + ay) + (az + aw);
        __syncthreads();
        // update: t<128 -> f-cell dim t ; 512<=t<640 -> b-cell dim t-512.
        // gate rows for both land at g[t], g[t+128], g[t+256], g[t+384].
        if ((t < NH) || (t >= 512 && t < 512 + NH)) {
            float gi = g[t], gf = g[t + NH], gg = g[t + 2 * NH], go = g[t + 3 * NH];
            cc = sigf(gf) * cc + sigf(gi) * tanhf(gg);
            float h = sigf(go) * tanhf(cc);
            if (t < NH) hF[t] = h; else hB[t - 512] = h;
        }
        __syncthreads();
        // out = concat(hF,hB) @ Wlin^T + blin
        if (t < NG) {
            const int j = t >> 5, ch = t & 31;
            const float* src = (ch < 16) ? &hF[ch * 8] : &hB[ch * 8 - NH];
            const float* wl  = Wlin + j * (2 * NH) + ch * 8;
            float p = 0.f;
#pragma unroll
            for (int q = 0; q < 8; ++q) p += src[q] * wl[q];
            prt[t] = p;
        }
        __syncthreads();
        if (t < NI) {
            float o = blin[t];
#pragma unroll
            for (int c2 = 0; c2 < 32; ++c2) o += prt[t * 32 + c2];
            out[(size_t)b * PRED * NI + s * NI + t] = o;
            inp[t] = o;
        }
        __syncthreads();
    }
}

extern "C" void kernel_launch(void* const* d_in, const int* in_sizes, int n_in,
                              void* d_out, int out_size, void* d_ws, size_t ws_size,
                              hipStream_t stream)
{
    const float* x      = (const float*)d_in[0];
    const float* eWih_f = (const float*)d_in[1];
    const float* eWhh_f = (const float*)d_in[2];
    const float* eb_f   = (const float*)d_in[3];
    const float* eWih_b = (const float*)d_in[4];
    const float* eWhh_b = (const float*)d_in[5];
    const float* eb_b   = (const float*)d_in[6];
    const float* dWih_f = (const float*)d_in[7];
    const float* dWhh_f = (const float*)d_in[8];
    const float* db_f   = (const float*)d_in[9];
    const float* dWih_b = (const float*)d_in[10];
    const float* dWhh_b = (const float*)d_in[11];
    const float* db_b   = (const float*)d_in[12];
    const float* Wlin   = (const float*)d_in[13];
    const float* blin   = (const float*)d_in[14];

    float* st = (float*)d_ws;  // NB*2*2*NH f32 encoder final states

    enc_kernel<<<256, 1024, 0, stream>>>(x, eWih_f, eWhh_f, eb_f, eWih_b, eWhh_b, eb_b, st);
    dec_kernel<<<256, 1024, 0, stream>>>(x, dWih_f, dWhh_f, db_f, dWih_b, dWhh_b, db_b,
                                         Wlin, blin, st, (float*)d_out);
}

// Round 5
// 3137.547 us; speedup vs baseline: 1.2609x; 1.2609x over previous
//
#include <hip/hip_runtime.h>
#include <math.h>

#define TB   720
#define NI   16
#define NH   128
#define NG   512   // 4*H
#define NB   256
#define PRED 96

// decoder reg/LDS split (R2 known-good)
#define WBR  56
#define WBL  72
#define WST  73

__device__ __forceinline__ float sigf(float v) { return 1.0f / (1.0f + __expf(-v)); }

#define L32(F) F(0)F(1)F(2)F(3)F(4)F(5)F(6)F(7)F(8)F(9)F(10)F(11)F(12)F(13)F(14)F(15)F(16)F(17)F(18)F(19)F(20)F(21)F(22)F(23)F(24)F(25)F(26)F(27)F(28)F(29)F(30)F(31)
#define L4(F)  F(0)F(1)F(2)F(3)

// ---------------- encoder ----------------
// grid 256 = (batch-pair) x (dir); block 512; thread t owns full gate row t
// for 2 batch elems. Weights in 36 NAMED float4 vars (no arrays -> no scratch
// fallback; R2-R4 showed arrays get demoted to scratch/reload). h via LDS
// broadcast reads (b128, same addr across lanes).
__global__ __attribute__((amdgpu_waves_per_eu(2, 2))) __launch_bounds__(512)
void enc_kernel(const float* __restrict__ x,
                const float* __restrict__ Wih_f, const float* __restrict__ Whh_f, const float* __restrict__ b_f,
                const float* __restrict__ Wih_b, const float* __restrict__ Whh_b, const float* __restrict__ b_b,
                float* __restrict__ st)   // st[b][dir][{h,c}][NH]
{
    __shared__ float xs0[TB * NI];
    __shared__ float xs1[TB * NI];
    __shared__ float hs0[NH], hs1[NH];
    __shared__ float gs0[NG], gs1[NG];

    const int wg  = blockIdx.x;
    const int dir = wg & 1;
    const int pb  = wg >> 1;
    const int b0  = 2 * pb, b1 = 2 * pb + 1;
    const int t   = threadIdx.x;

    const float* Wih = dir ? Wih_b : Wih_f;
    const float* Whh = dir ? Whh_b : Whh_f;
    const float* bv  = dir ? b_b   : b_f;

    // stage both batch elements' x (coalesced float4)
    {
        const float4* xg0 = (const float4*)(x + (size_t)b0 * TB * NI);
        const float4* xg1 = (const float4*)(x + (size_t)b1 * TB * NI);
        float4* s0 = (float4*)xs0;
        float4* s1 = (float4*)xs1;
        for (int i = t; i < TB * NI / 4; i += 512) { s0[i] = xg0[i]; s1[i] = xg1[i]; }
    }

    // ---- weights: named registers only ----
    float4 wx0, wx1, wx2, wx3;
#define DW(K) float4 wh##K;
    L32(DW)
#undef DW
    {
        const float4* Up = (const float4*)(Wih + t * NI);
        wx0 = Up[0]; wx1 = Up[1]; wx2 = Up[2]; wx3 = Up[3];
        const float4* Wp = (const float4*)(Whh + t * NH);
#define LW(K) wh##K = Wp[K];
        L32(LW)
#undef LW
    }
    const float bias = bv[t];

    if (t < NH) { hs0[t] = 0.0f; hs1[t] = 0.0f; }
    float cc = 0.0f;   // t<128: c of b0 dim t ; 128<=t<256: c of b1 dim t-128
    __syncthreads();

    for (int s = 0; s < TB; ++s) {
        const int tt = dir ? (TB - 1 - s) : s;
        const float4* xp0 = (const float4*)(xs0 + tt * NI);
        const float4* xp1 = (const float4*)(xs1 + tt * NI);
        float a0x = bias, a0y = 0.f, a0z = 0.f, a0w = 0.f;
        float a1x = bias, a1y = 0.f, a1z = 0.f, a1w = 0.f;
#define FX(K) { float4 v0 = xp0[K]; float4 v1 = xp1[K]; \
    a0x += wx##K.x * v0.x; a0y += wx##K.y * v0.y; a0z += wx##K.z * v0.z; a0w += wx##K.w * v0.w; \
    a1x += wx##K.x * v1.x; a1y += wx##K.y * v1.y; a1z += wx##K.z * v1.z; a1w += wx##K.w * v1.w; }
        L4(FX)
#undef FX
        const float4* h0v = (const float4*)hs0;
        const float4* h1v = (const float4*)hs1;
#define FH(K) { float4 v0 = h0v[K]; float4 v1 = h1v[K]; \
    a0x += wh##K.x * v0.x; a0y += wh##K.y * v0.y; a0z += wh##K.z * v0.z; a0w += wh##K.w * v0.w; \
    a1x += wh##K.x * v1.x; a1y += wh##K.y * v1.y; a1z += wh##K.z * v1.z; a1w += wh##K.w * v1.w; }
        L32(FH)
#undef FH
        gs0[t] = (a0x + a0y) + (a0z + a0w);
        gs1[t] = (a1x + a1y) + (a1z + a1w);
        __syncthreads();
        if (t < 256) {
            const int d = t & 127;
            const float* gp = (t < 128) ? gs0 : gs1;
            float gi = gp[d], gf = gp[d + 128], gg = gp[d + 256], go = gp[d + 384];
            cc = sigf(gf) * cc + sigf(gi) * tanhf(gg);
            float h = sigf(go) * tanhf(cc);
            if (t < 128) hs0[d] = h; else hs1[d] = h;
        }
        __syncthreads();
    }

    if (t < NH) {
        st[((b0 * 2 + dir) * 2 + 0) * NH + t] = hs0[t];
        st[((b0 * 2 + dir) * 2 + 1) * NH + t] = cc;
    } else if (t < 2 * NH) {
        const int d = t - NH;
        st[((b1 * 2 + dir) * 2 + 0) * NH + d] = hs1[d];
        st[((b1 * 2 + dir) * 2 + 1) * NH + d] = cc;
    }
}

// ---------------- decoder (R2 known-good: 358 us) ----------------
__global__ __launch_bounds__(512, 1)
void dec_kernel(const float* __restrict__ x,
                const float* __restrict__ Wih_f, const float* __restrict__ Whh_f, const float* __restrict__ b_f,
                const float* __restrict__ Wih_b, const float* __restrict__ Whh_b, const float* __restrict__ b_b,
                const float* __restrict__ Wlin, const float* __restrict__ blin,
                const float* __restrict__ st, float* __restrict__ out)
{
    __shared__ float wbl[NG * WST];   // 512*73*4 = 149504 B
    __shared__ float hF[NH], hB[NH];
    __shared__ float inp[NI];
    __shared__ float gF[NG], gB[NG];
    __shared__ float prt[NG];

    const int b = blockIdx.x;
    const int t = threadIdx.x;

#pragma unroll
    for (int k = 0; k < WBL / 4; ++k) {
        float4 v = ((const float4*)(Whh_b + t * NH + WBR))[k];
        wbl[t * WST + 4*k]     = v.x;
        wbl[t * WST + 4*k + 1] = v.y;
        wbl[t * WST + 4*k + 2] = v.z;
        wbl[t * WST + 4*k + 3] = v.w;
    }

    float wf[NH];
#pragma unroll
    for (int k = 0; k < NH / 4; ++k) {
        float4 v = ((const float4*)(Whh_f + t * NH))[k];
        wf[4*k] = v.x; wf[4*k+1] = v.y; wf[4*k+2] = v.z; wf[4*k+3] = v.w;
    }
    float wb[WBR];
#pragma unroll
    for (int k = 0; k < WBR / 4; ++k) {
        float4 v = ((const float4*)(Whh_b + t * NH))[k];
        wb[4*k] = v.x; wb[4*k+1] = v.y; wb[4*k+2] = v.z; wb[4*k+3] = v.w;
    }
    float uf[NI], ub[NI];
#pragma unroll
    for (int k = 0; k < NI / 4; ++k) {
        float4 vf = ((const float4*)(Wih_f + t * NI))[k];
        float4 vb = ((const float4*)(Wih_b + t * NI))[k];
        uf[4*k] = vf.x; uf[4*k+1] = vf.y; uf[4*k+2] = vf.z; uf[4*k+3] = vf.w;
        ub[4*k] = vb.x; ub[4*k+1] = vb.y; ub[4*k+2] = vb.z; ub[4*k+3] = vb.w;
    }
    const float bf = b_f[t], bb = b_b[t];

    float cc = 0.0f;
    if (t < NH) {
        hF[t] = st[((b * 2 + 0) * 2 + 0) * NH + t];
        cc    = st[((b * 2 + 0) * 2 + 1) * NH + t];
    } else if (t < 2 * NH) {
        const int d = t - NH;
        hB[d] = st[((b * 2 + 1) * 2 + 0) * NH + d];
        cc    = st[((b * 2 + 1) * 2 + 1) * NH + d];
    }
    if (t < NI) inp[t] = x[(size_t)b * TB * NI + (TB - 1) * NI + t];
    __syncthreads();

    for (int s = 0; s < PRED; ++s) {
        float aF = bf, aB = bb;
#pragma unroll
        for (int j = 0; j < NI; ++j) { float v = inp[j]; aF += v * uf[j]; aB += v * ub[j]; }
        const float4* h4F = (const float4*)hF;
#pragma unroll
        for (int k = 0; k < NH / 4; ++k) {
            float4 v = h4F[k];
            aF += v.x * wf[4*k] + v.y * wf[4*k+1] + v.z * wf[4*k+2] + v.w * wf[4*k+3];
        }
#pragma unroll
        for (int k = 0; k < WBR; ++k) aB += hB[k] * wb[k];
#pragma unroll
        for (int j = 0; j < WBL; ++j) aB += hB[WBR + j] * wbl[t * WST + j];
        gF[t] = aF;
        gB[t] = aB;
        __syncthreads();
        if (t < NH) {
            float gi = gF[t], gfr = gF[t + NH], gg = gF[t + 2 * NH], go = gF[t + 3 * NH];
            cc = sigf(gfr) * cc + sigf(gi) * tanhf(gg);
            hF[t] = sigf(go) * tanhf(cc);
        } else if (t < 2 * NH) {
            const int d = t - NH;
            float gi = gB[d], gfr = gB[d + NH], gg = gB[d + 2 * NH], go = gB[d + 3 * NH];
            cc = sigf(gfr) * cc + sigf(gi) * tanhf(gg);
            hB[d] = sigf(go) * tanhf(cc);
        }
        __syncthreads();
        const int j = t >> 5, ch = t & 31;
        const float* src = (ch < 16) ? &hF[ch * 8] : &hB[ch * 8 - NH];
        const float* wl  = Wlin + j * (2 * NH) + ch * 8;
        float p = 0.0f;
#pragma unroll
        for (int q = 0; q < 8; ++q) p += src[q] * wl[q];
        prt[t] = p;
        __syncthreads();
        if (t < NI) {
            float o = blin[t];
#pragma unroll
            for (int c2 = 0; c2 < 32; ++c2) o += prt[t * 32 + c2];
            out[(size_t)b * PRED * NI + s * NI + t] = o;
            inp[t] = o;
        }
        __syncthreads();
    }
}

extern "C" void kernel_launch(void* const* d_in, const int* in_sizes, int n_in,
                              void* d_out, int out_size, void* d_ws, size_t ws_size,
                              hipStream_t stream)
{
    const float* x      = (const float*)d_in[0];
    const float* eWih_f = (const float*)d_in[1];
    const float* eWhh_f = (const float*)d_in[2];
    const float* eb_f   = (const float*)d_in[3];
    const float* eWih_b = (const float*)d_in[4];
    const float* eWhh_b = (const float*)d_in[5];
    const float* eb_b   = (const float*)d_in[6];
    const float* dWih_f = (const float*)d_in[7];
    const float* dWhh_f = (const float*)d_in[8];
    const float* db_f   = (const float*)d_in[9];
    const float* dWih_b = (const float*)d_in[10];
    const float* dWhh_b = (const float*)d_in[11];
    const float* db_b   = (const float*)d_in[12];
    const float* Wlin   = (const float*)d_in[13];
    const float* blin   = (const float*)d_in[14];

    float* st = (float*)d_ws;  // NB*2*2*NH f32 encoder final states

    enc_kernel<<<256, 512, 0, stream>>>(x, eWih_f, eWhh_f, eb_f, eWih_b, eWhh_b, eb_b, st);
    dec_kernel<<<256, 512, 0, stream>>>(x, dWih_f, dWhh_f, db_f, dWih_b, dWhh_b, db_b,
                                        Wlin, blin, st, (float*)d_out);
}

// Round 6
// 1341.311 us; speedup vs baseline: 2.9495x; 2.3392x over previous
//
#include <hip/hip_runtime.h>
#include <math.h>

#define TB   720
#define NI   16
#define NH   128
#define NG   512   // 4*H
#define PRED 96

// decoder reg/LDS split (R2 known-good)
#define WBR  56
#define WBL  72
#define WST  73

typedef _Float16 h2 __attribute__((ext_vector_type(2)));

__device__ __forceinline__ float sigf(float v) { return 1.0f / (1.0f + __expf(-v)); }

// packed-f16 dot2 with f32 accumulate (v_dot2_f32_f16)
__device__ __forceinline__ float fdot2f(unsigned int a, unsigned int b, float c) {
#if __has_builtin(__builtin_amdgcn_fdot2)
    return __builtin_amdgcn_fdot2(__builtin_bit_cast(h2, a), __builtin_bit_cast(h2, b), c, false);
#else
    h2 x = __builtin_bit_cast(h2, a), y = __builtin_bit_cast(h2, b);
    return c + (float)x.x * (float)y.x + (float)x.y * (float)y.y;
#endif
}

__device__ __forceinline__ unsigned int packf16(float a, float b) {
    h2 p; p.x = (_Float16)a; p.y = (_Float16)b;
    return __builtin_bit_cast(unsigned int, p);
}

// ---------------- encoder ----------------
// grid 512 = batch x dir; block 512; thread t owns gate row t of ONE unit.
// Weights as 72 packed-f16 dwords/thread => ~110 VGPR, UNDER the 128 cap the
// allocator enforced in R2-R5 (no spill, no reload). 26KB LDS -> 2 blocks/CU,
// 4 waves/SIMD. fdot2 halves VALU and LDS-broadcast counts vs f32.
__global__ __launch_bounds__(512, 4)
void enc_kernel(const float* __restrict__ x,
                const float* __restrict__ Wih_f, const float* __restrict__ Whh_f, const float* __restrict__ b_f,
                const float* __restrict__ Wih_b, const float* __restrict__ Whh_b, const float* __restrict__ b_b,
                float* __restrict__ st)   // st[b][dir][{h,c}][NH]
{
    __shared__ unsigned int xsh[TB * NI / 2];  // x as f16 pairs: 5760 dw = 23KB
    __shared__ unsigned int hsh[NH / 2];       // h as f16 pairs: 64 dw
    __shared__ float gs[NG];

    const int wg  = blockIdx.x;
    const int dir = wg & 1;
    const int b   = wg >> 1;
    const int t   = threadIdx.x;

    const float* Wih = dir ? Wih_b : Wih_f;
    const float* Whh = dir ? Whh_b : Whh_f;
    const float* bv  = dir ? b_b   : b_f;

    // stage x -> f16 (coalesced float2 reads)
    {
        const float2* xg = (const float2*)(x + (size_t)b * TB * NI);
        for (int i = t; i < TB * NI / 2; i += 512) {
            float2 v = xg[i];
            xsh[i] = packf16(v.x, v.y);
        }
    }

    // weights -> packed f16 registers (72 dwords)
    unsigned int wx[8];
    unsigned int wh[64];
#pragma unroll
    for (int k = 0; k < 8; ++k) {
        float2 v = ((const float2*)(Wih + t * NI))[k];
        wx[k] = packf16(v.x, v.y);
    }
#pragma unroll
    for (int k = 0; k < 64; ++k) {
        float2 v = ((const float2*)(Whh + t * NH))[k];
        wh[k] = packf16(v.x, v.y);
    }
    const float bias = bv[t];

    if (t < NH / 2) hsh[t] = 0u;
    float cc = 0.0f, hlast = 0.0f;
    __syncthreads();

    for (int s = 0; s < TB; ++s) {
        const int tt = dir ? (TB - 1 - s) : s;
        float a0 = bias, a1 = 0.f, a2 = 0.f, a3 = 0.f;
        // x part: 16 f16 = 2 uint4 broadcasts
        const uint4* xv = (const uint4*)(xsh + tt * 8);
        uint4 qa = xv[0], qb = xv[1];
        a0 = fdot2f(qa.x, wx[0], a0); a1 = fdot2f(qa.y, wx[1], a1);
        a2 = fdot2f(qa.z, wx[2], a2); a3 = fdot2f(qa.w, wx[3], a3);
        a0 = fdot2f(qb.x, wx[4], a0); a1 = fdot2f(qb.y, wx[5], a1);
        a2 = fdot2f(qb.z, wx[6], a2); a3 = fdot2f(qb.w, wx[7], a3);
        // h part: 128 f16 = 16 uint4 broadcasts, 64 dot2
        const uint4* hv = (const uint4*)hsh;
#pragma unroll
        for (int k = 0; k < 16; ++k) {
            uint4 q = hv[k];
            a0 = fdot2f(q.x, wh[4*k + 0], a0);
            a1 = fdot2f(q.y, wh[4*k + 1], a1);
            a2 = fdot2f(q.z, wh[4*k + 2], a2);
            a3 = fdot2f(q.w, wh[4*k + 3], a3);
        }
        gs[t] = (a0 + a1) + (a2 + a3);
        __syncthreads();
        if (t < NH) {
            float gi = gs[t], gf = gs[t + NH], gg = gs[t + 2 * NH], go = gs[t + 3 * NH];
            cc = sigf(gf) * cc + sigf(gi) * tanhf(gg);
            hlast = sigf(go) * tanhf(cc);
            ((_Float16*)hsh)[t] = (_Float16)hlast;   // ds_write_b16
        }
        __syncthreads();
    }

    if (t < NH) {
        st[((b * 2 + dir) * 2 + 0) * NH + t] = hlast;
        st[((b * 2 + dir) * 2 + 1) * NH + t] = cc;
    }
}

// ---------------- decoder (R2 known-good) ----------------
__global__ __launch_bounds__(512, 1)
void dec_kernel(const float* __restrict__ x,
                const float* __restrict__ Wih_f, const float* __restrict__ Whh_f, const float* __restrict__ b_f,
                const float* __restrict__ Wih_b, const float* __restrict__ Whh_b, const float* __restrict__ b_b,
                const float* __restrict__ Wlin, const float* __restrict__ blin,
                const float* __restrict__ st, float* __restrict__ out)
{
    __shared__ float wbl[NG * WST];   // 512*73*4 = 149504 B
    __shared__ float hF[NH], hB[NH];
    __shared__ float inp[NI];
    __shared__ float gF[NG], gB[NG];
    __shared__ float prt[NG];

    const int b = blockIdx.x;
    const int t = threadIdx.x;

#pragma unroll
    for (int k = 0; k < WBL / 4; ++k) {
        float4 v = ((const float4*)(Whh_b + t * NH + WBR))[k];
        wbl[t * WST + 4*k]     = v.x;
        wbl[t * WST + 4*k + 1] = v.y;
        wbl[t * WST + 4*k + 2] = v.z;
        wbl[t * WST + 4*k + 3] = v.w;
    }

    float wf[NH];
#pragma unroll
    for (int k = 0; k < NH / 4; ++k) {
        float4 v = ((const float4*)(Whh_f + t * NH))[k];
        wf[4*k] = v.x; wf[4*k+1] = v.y; wf[4*k+2] = v.z; wf[4*k+3] = v.w;
    }
    float wb[WBR];
#pragma unroll
    for (int k = 0; k < WBR / 4; ++k) {
        float4 v = ((const float4*)(Whh_b + t * NH))[k];
        wb[4*k] = v.x; wb[4*k+1] = v.y; wb[4*k+2] = v.z; wb[4*k+3] = v.w;
    }
    float uf[NI], ub[NI];
#pragma unroll
    for (int k = 0; k < NI / 4; ++k) {
        float4 vf = ((const float4*)(Wih_f + t * NI))[k];
        float4 vb = ((const float4*)(Wih_b + t * NI))[k];
        uf[4*k] = vf.x; uf[4*k+1] = vf.y; uf[4*k+2] = vf.z; uf[4*k+3] = vf.w;
        ub[4*k] = vb.x; ub[4*k+1] = vb.y; ub[4*k+2] = vb.z; ub[4*k+3] = vb.w;
    }
    const float bf = b_f[t], bb = b_b[t];

    float cc = 0.0f;
    if (t < NH) {
        hF[t] = st[((b * 2 + 0) * 2 + 0) * NH + t];
        cc    = st[((b * 2 + 0) * 2 + 1) * NH + t];
    } else if (t < 2 * NH) {
        const int d = t - NH;
        hB[d] = st[((b * 2 + 1) * 2 + 0) * NH + d];
        cc    = st[((b * 2 + 1) * 2 + 1) * NH + d];
    }
    if (t < NI) inp[t] = x[(size_t)b * TB * NI + (TB - 1) * NI + t];
    __syncthreads();

    for (int s = 0; s < PRED; ++s) {
        float aF = bf, aB = bb;
#pragma unroll
        for (int j = 0; j < NI; ++j) { float v = inp[j]; aF += v * uf[j]; aB += v * ub[j]; }
        const float4* h4F = (const float4*)hF;
#pragma unroll
        for (int k = 0; k < NH / 4; ++k) {
            float4 v = h4F[k];
            aF += v.x * wf[4*k] + v.y * wf[4*k+1] + v.z * wf[4*k+2] + v.w * wf[4*k+3];
        }
#pragma unroll
        for (int k = 0; k < WBR; ++k) aB += hB[k] * wb[k];
#pragma unroll
        for (int j = 0; j < WBL; ++j) aB += hB[WBR + j] * wbl[t * WST + j];
        gF[t] = aF;
        gB[t] = aB;
        __syncthreads();
        if (t < NH) {
            float gi = gF[t], gfr = gF[t + NH], gg = gF[t + 2 * NH], go = gF[t + 3 * NH];
            cc = sigf(gfr) * cc + sigf(gi) * tanhf(gg);
            hF[t] = sigf(go) * tanhf(cc);
        } else if (t < 2 * NH) {
            const int d = t - NH;
            float gi = gB[d], gfr = gB[d + NH], gg = gB[d + 2 * NH], go = gB[d + 3 * NH];
            cc = sigf(gfr) * cc + sigf(gi) * tanhf(gg);
            hB[d] = sigf(go) * tanhf(cc);
        }
        __syncthreads();
        const int j = t >> 5, ch = t & 31;
        const float* src = (ch < 16) ? &hF[ch * 8] : &hB[ch * 8 - NH];
        const float* wl  = Wlin + j * (2 * NH) + ch * 8;
        float p = 0.0f;
#pragma unroll
        for (int q = 0; q < 8; ++q) p += src[q] * wl[q];
        prt[t] = p;
        __syncthreads();
        if (t < NI) {
            float o = blin[t];
#pragma unroll
            for (int c2 = 0; c2 < 32; ++c2) o += prt[t * 32 + c2];
            out[(size_t)b * PRED * NI + s * NI + t] = o;
            inp[t] = o;
        }
        __syncthreads();
    }
}

extern "C" void kernel_launch(void* const* d_in, const int* in_sizes, int n_in,
                              void* d_out, int out_size, void* d_ws, size_t ws_size,
                              hipStream_t stream)
{
    const float* x      = (const float*)d_in[0];
    const float* eWih_f = (const float*)d_in[1];
    const float* eWhh_f = (const float*)d_in[2];
    const float* eb_f   = (const float*)d_in[3];
    const float* eWih_b = (const float*)d_in[4];
    const float* eWhh_b = (const float*)d_in[5];
    const float* eb_b   = (const float*)d_in[6];
    const float* dWih_f = (const float*)d_in[7];
    const float* dWhh_f = (const float*)d_in[8];
    const float* db_f   = (const float*)d_in[9];
    const float* dWih_b = (const float*)d_in[10];
    const float* dWhh_b = (const float*)d_in[11];
    const float* db_b   = (const float*)d_in[12];
    const float* Wlin   = (const float*)d_in[13];
    const float* blin   = (const float*)d_in[14];

    float* st = (float*)d_ws;  // 256*2*2*128 f32 encoder final states

    enc_kernel<<<512, 512, 0, stream>>>(x, eWih_f, eWhh_f, eb_f, eWih_b, eWhh_b, eb_b, st);
    dec_kernel<<<256, 512, 0, stream>>>(x, dWih_f, dWhh_f, db_f, dWih_b, dWhh_b, db_b,
                                        Wlin, blin, st, (float*)d_out);
}